// Round 19
// baseline (234.846 us; speedup 1.0000x reference)
//
#include <hip/hip_runtime.h>
#include <math.h>

#define HW 16384
#define NB 2
#define NC 192

typedef __attribute__((ext_vector_type(8))) short bh8;
typedef __attribute__((ext_vector_type(4))) float f32x4;

__device__ inline ushort f2bf(float f) {
  union { float f; unsigned int u; } x; x.f = f;
  unsigned int r = x.u + 0x7fffu + ((x.u >> 16) & 1u);
  return (ushort)(r >> 16);
}
__device__ inline float bf2f(ushort u) {
  union { unsigned int i; float f; } x; x.i = ((unsigned int)u) << 16;
  return x.f;
}
__device__ inline float asf(unsigned int u) {
  union { unsigned int i; float f; } x; x.i = u; return x.f;
}
__device__ inline unsigned int cvtpk(float lo, float hi) {
  unsigned int r;
  asm("v_cvt_pk_bf16_f32 %0, %1, %2" : "=v"(r) : "v"(lo), "v"(hi));
  return r;
}
__device__ inline void gl16(const ushort* g, char* l) {
  __builtin_amdgcn_global_load_lds(
      (const __attribute__((address_space(1))) unsigned int*)g,
      (__attribute__((address_space(3))) unsigned int*)l, 16, 0, 0);
}

// ---------------------------------------------------------------------------
// Kernel 0a: pack conv weights -> wpack[s=108][o=192][kk=32] bf16 (in d_out)
// ---------------------------------------------------------------------------
__global__ void k_wpack(const float* __restrict__ w1, ushort* __restrict__ wpack) {
  int i = blockIdx.x * 256 + threadIdx.x;  // 663552
  int s = i / 6144;
  int rem = i - s * 6144;
  int o = rem >> 5, kk = rem & 31;
  int dy = s / 36, t2 = s - dy * 36;
  int icc = t2 / 3, dxi = t2 - icc * 3;
  int ic = icc * 32 + kk;
  wpack[i] = f2bf(w1[(size_t)o * 3456 + (size_t)ic * 9 + dy * 3 + dxi]);
}

// ---------------------------------------------------------------------------
// Kernel 0b: pack GEMM weights -> wg[768][192] bf16.
// ---------------------------------------------------------------------------
__global__ void k_wgpack(const float* __restrict__ wq, const float* __restrict__ wkv,
                         const float* __restrict__ wp, float scale,
                         ushort* __restrict__ wg) {
  int i = blockIdx.x * 256 + threadIdx.x;  // 147456
  int r = i / NC, c = i - r * NC;
  float v;
  if (r < 192) {
    int orow = (r & 31) * 6 + (r >> 5);
    v = wq[(size_t)orow * NC + c] * scale;
  } else if (r < 576) {
    int rp = r - 192;
    int t = rp >= 192 ? 1 : 0;
    int cc = rp - t * 192;
    int orow = t * 192 + (cc & 31) * 6 + (cc >> 5);
    v = wkv[(size_t)orow * NC + c];
  } else {
    int rp = r - 576;
    v = wp[(size_t)rp * NC + ((c & 31) * 6 + (c >> 5))];
  }
  wg[i] = f2bf(v);
}

// ---------------------------------------------------------------------------
// Kernel 0d: zero ONLY the halo of xpp. c = i % 48 (48 not a power of two).
// ---------------------------------------------------------------------------
__global__ void k_zerohalo(ushort* __restrict__ xpp) {
  int i = blockIdx.x * 256 + threadIdx.x;  // exactly 195*256 = 49920
  int t = i / 48;          // 0..1039
  int c = i - t * 48;      // 0..47
  int b = t / 520;
  int slot = t - b * 520;
  int row, px;
  if (slot < 132) { row = 0; px = slot; }
  else if (slot < 264) { row = 129; px = slot - 132; }
  else { int j = slot - 264; row = 1 + (j >> 1); px = (j & 1) ? 131 : 0; }
  *(uint4*)(xpp + ((size_t)(b * 130 + row) * 132 + px) * 384 + c * 8) =
      make_uint4(0u, 0u, 0u, 0u);
}

// ---------------------------------------------------------------------------
// Kernel 0c: x fp32 NCHW -> xpp bf16 padded NHWC [b][130 rows][132 px][384].
// ---------------------------------------------------------------------------
__global__ __launch_bounds__(256) void k_xpack(const float* __restrict__ xq,
                                               const float* __restrict__ xkv,
                                               ushort* __restrict__ xpp) {
  __shared__ float t[NC][65];
  const int tid = threadIdx.x;
  const size_t r0 = (size_t)blockIdx.x * 64;
  const int b = (int)(r0 >> 14);
  const int px0 = (int)(r0 & 16383);
  const int y = px0 >> 7, x0 = px0 & 127;
  const float* src = (blockIdx.y == 0 ? xq : xkv) + (size_t)b * NC * HW + px0;
#pragma unroll
  for (int it = 0; it < 12; ++it) {
    int i = it * 256 + tid;  // 3072
    int c = i >> 4, q4 = i & 15;
    float4 v = *(const float4*)(src + (size_t)c * HW + q4 * 4);
    t[c][q4 * 4 + 0] = v.x; t[c][q4 * 4 + 1] = v.y;
    t[c][q4 * 4 + 2] = v.z; t[c][q4 * 4 + 3] = v.w;
  }
  __syncthreads();
  ushort* dst = xpp + ((size_t)(b * 130 + y + 1) * 132 + x0 + 1) * 384 +
                blockIdx.y * 192;
#pragma unroll
  for (int it = 0; it < 6; ++it) {
    int i = it * 256 + tid;  // 1536
    int px = i / 24, ch = i - px * 24;
    ushort4 u0, u1;
    u0.x = f2bf(t[ch * 8 + 0][px]); u0.y = f2bf(t[ch * 8 + 1][px]);
    u0.z = f2bf(t[ch * 8 + 2][px]); u0.w = f2bf(t[ch * 8 + 3][px]);
    u1.x = f2bf(t[ch * 8 + 4][px]); u1.y = f2bf(t[ch * 8 + 5][px]);
    u1.z = f2bf(t[ch * 8 + 6][px]); u1.w = f2bf(t[ch * 8 + 7][px]);
    *(ushort4*)&dst[(size_t)px * 384 + ch * 8] = u0;
    *(ushort4*)&dst[(size_t)px * 384 + ch * 8 + 4] = u1;
  }
}

// ---------------------------------------------------------------------------
// MFMA GEMM engine helpers.
// ---------------------------------------------------------------------------
__device__ inline void stage64(ushort* lds, const ushort* src, int rowStride,
                               int tid) {
#pragma unroll
  for (int it = 0; it < 6; ++it) {
    int i = it * 256 + tid;  // 1536
    int row = i / 24, c = i - row * 24;
    int pos = (c & 24) | ((c & 7) ^ (row & 7));
    uint4 v = *(const uint4*)(src + (size_t)row * rowStride + c * 8);
    *(uint4*)&lds[row * NC + pos * 8] = v;
  }
}
__device__ inline bh8 frag64(const ushort* lds, int row, int c) {
  int pos = (c & 24) | ((c & 7) ^ (row & 7));
  return *(const bh8*)&lds[row * NC + pos * 8];
}

// ---------------------------------------------------------------------------
// Merged q/k/v GEMM: blockIdx.y = 0:q 1:k 2:v. x-tile staged once, loop 3 o-tiles.
// k/v write INTERLEAVED kvb[px][j][k4|v4] (16B per (px,j)).
// ---------------------------------------------------------------------------
__global__ __launch_bounds__(256) void k_gemm_mfma(
    const ushort* __restrict__ xpp, const ushort* __restrict__ wg,
    ushort* __restrict__ qb, ushort* __restrict__ kvb) {
  __shared__ __attribute__((aligned(16))) ushort xs[64 * NC];
  __shared__ __attribute__((aligned(16))) ushort ws2[64 * NC];
  const int tid = threadIdx.x;
  const size_t p0 = (size_t)blockIdx.x * 64;
  const int bb = (int)(p0 >> 14);
  const int yy = (int)((p0 >> 7) & 127);
  const int xx0 = (int)(p0 & 127);
  const int which = blockIdx.y;
  const int cOff = (which == 0) ? 0 : 192;
  const ushort* src = xpp + ((size_t)(bb * 130 + yy + 1) * 132 + xx0 + 1) * 384 + cOff;
  const ushort* wbase = wg + (size_t)(which * 192) * NC;
  stage64(xs, src, 384, tid);
  const int lid = tid & 15, g = (tid >> 4) & 3, wv = tid >> 6;
  const int wo = (wv & 1) * 32, wp = (wv >> 1) * 32;
  const int vofs = (which == 2) ? 4 : 0;
  for (int ot = 0; ot < 3; ++ot) {
    if (ot) __syncthreads();
    stage64(ws2, wbase + (size_t)(ot * 64) * NC, NC, tid);
    __syncthreads();
    f32x4 acc[2][2];
#pragma unroll
    for (int m = 0; m < 2; ++m)
#pragma unroll
      for (int n = 0; n < 2; ++n) acc[m][n] = (f32x4){0.f, 0.f, 0.f, 0.f};
#pragma unroll
    for (int k = 0; k < 6; ++k) {
      bh8 a0 = frag64(ws2, wo + lid, k * 4 + g);
      bh8 a1 = frag64(ws2, wo + 16 + lid, k * 4 + g);
      bh8 b0 = frag64(xs, wp + lid, k * 4 + g);
      bh8 b1 = frag64(xs, wp + 16 + lid, k * 4 + g);
      acc[0][0] = __builtin_amdgcn_mfma_f32_16x16x32_bf16(a0, b0, acc[0][0], 0, 0, 0);
      acc[0][1] = __builtin_amdgcn_mfma_f32_16x16x32_bf16(a0, b1, acc[0][1], 0, 0, 0);
      acc[1][0] = __builtin_amdgcn_mfma_f32_16x16x32_bf16(a1, b0, acc[1][0], 0, 0, 0);
      acc[1][1] = __builtin_amdgcn_mfma_f32_16x16x32_bf16(a1, b1, acc[1][1], 0, 0, 0);
    }
    const int od = ot * 64;
#pragma unroll
    for (int m = 0; m < 2; ++m)
#pragma unroll
      for (int n = 0; n < 2; ++n) {
        int orow = od + wo + m * 16 + g * 4;
        size_t px = p0 + wp + n * 16 + lid;
        ushort4 u;
        u.x = f2bf(acc[m][n][0]); u.y = f2bf(acc[m][n][1]);
        u.z = f2bf(acc[m][n][2]); u.w = f2bf(acc[m][n][3]);
        if (which == 0)
          *(ushort4*)&qb[px * NC + orow] = u;
        else
          *(ushort4*)&kvb[px * 384 + orow * 2 + vofs] = u;
      }
  }
}

__global__ __launch_bounds__(256) void k_proj_mfma(
    const ushort* __restrict__ pre, const ushort* __restrict__ wg,
    const float* __restrict__ bp, float* __restrict__ out) {
  __shared__ __attribute__((aligned(16))) ushort xs[64 * NC];
  __shared__ __attribute__((aligned(16))) ushort ws2[64 * NC];
  const int tid = threadIdx.x;
  const size_t p0 = (size_t)blockIdx.x * 64;
  const int o0 = blockIdx.y * 64;
  stage64(xs, pre + p0 * NC, NC, tid);
  stage64(ws2, wg + (size_t)o0 * NC, NC, tid);
  __syncthreads();
  const int lid = tid & 15, g = (tid >> 4) & 3, wv = tid >> 6;
  const int wo = (wv & 1) * 32, wp = (wv >> 1) * 32;
  f32x4 acc[2][2];
#pragma unroll
  for (int m = 0; m < 2; ++m)
#pragma unroll
    for (int n = 0; n < 2; ++n) acc[m][n] = (f32x4){0.f, 0.f, 0.f, 0.f};
#pragma unroll
  for (int k = 0; k < 6; ++k) {
    bh8 a0 = frag64(ws2, wo + lid, k * 4 + g);
    bh8 a1 = frag64(ws2, wo + 16 + lid, k * 4 + g);
    bh8 b0 = frag64(xs, wp + lid, k * 4 + g);
    bh8 b1 = frag64(xs, wp + 16 + lid, k * 4 + g);
    acc[0][0] = __builtin_amdgcn_mfma_f32_16x16x32_bf16(a0, b0, acc[0][0], 0, 0, 0);
    acc[0][1] = __builtin_amdgcn_mfma_f32_16x16x32_bf16(a0, b1, acc[0][1], 0, 0, 0);
    acc[1][0] = __builtin_amdgcn_mfma_f32_16x16x32_bf16(a1, b0, acc[1][0], 0, 0, 0);
    acc[1][1] = __builtin_amdgcn_mfma_f32_16x16x32_bf16(a1, b1, acc[1][1], 0, 0, 0);
  }
#pragma unroll
  for (int m = 0; m < 2; ++m)
#pragma unroll
    for (int n = 0; n < 2; ++n) {
      int oc = o0 + wo + m * 16 + g * 4;
      size_t pxf = p0 + wp + n * 16 + lid;
      int b = (int)(pxf >> 14);
      int px = (int)(pxf & 16383);
#pragma unroll
      for (int j = 0; j < 4; ++j)
        out[((size_t)b * NC + oc + j) * HW + px] = acc[m][n][j] + bp[oc + j];
    }
}

// ---------------------------------------------------------------------------
// Kernel 2 v8: R17 structure (W+P LDS dbuf, 1 barrier/step, T1 swizzle) with
// K SPLIT: half 0 = icc 0..5 (+bias), half 1 = icc 6..11. Grid 1024 ->
// 3 blocks/CU resident (3x53.76KB <= 160KiB). Partials bf16, NO relu;
// k_offhead fuses relu(pa+pb).
// ---------------------------------------------------------------------------
#define CP0 0
#define CP1 8448
#define CW0 16896
#define CW1 35328
__global__ __launch_bounds__(256, 3) void k_conv_mfma(
    const ushort* __restrict__ xpp, const ushort* __restrict__ wpack,
    const float* __restrict__ b1, ushort* __restrict__ h1a,
    ushort* __restrict__ h1b) {
  __shared__ __attribute__((aligned(16))) char smem[53760];
  const int tid = threadIdx.x;
  // XCD swizzle over 1024 blocks: each XCD gets 128 contiguous logical ids.
  const int logical = (blockIdx.x & 7) * 128 + (blockIdx.x >> 3);
  const int half = logical >> 9;      // 0: icc 0-5, 1: icc 6-11
  const int bi = logical & 511;
  const int b = bi >> 8;
  const int y = (bi >> 1) & 127;
  const int oh = bi & 1;
  const int iccB = half * 6;
  const int lid = tid & 15;
  const int g = (tid >> 4) & 3;
  const int wv = tid >> 6;
  const int lane = tid & 63;
  const int og = wv & 1;
  const int pg = wv >> 1;
  f32x4 acc[3][4];
#pragma unroll
  for (int m = 0; m < 3; ++m)
#pragma unroll
    for (int n = 0; n < 4; ++n) acc[m][n] = (f32x4){0.f, 0.f, 0.f, 0.f};

  auto stageP = [&](int icc, int dy, int buf) {
    const size_t rowbase = (size_t)(b * 130 + y + dy) * 132 * 384 + icc * 32;
    char* dst0 = smem + (buf ? CP1 : CP0);
    for (int grp = wv; grp < 9; grp += 4) {
      int i = grp * 64 + lane;
      if (i < 528) {
        int slot = i >> 2, ch = i & 3;
        gl16(xpp + rowbase + (size_t)slot * 384 + ((ch ^ ((slot >> 1) & 3)) << 3),
             dst0 + grp * 1024);
      }
    }
  };
  auto stageW = [&](int icc, int dy, int buf) {
    const ushort* wsrc = wpack + (size_t)((dy * 12 + icc) * 3) * 6144 + oh * 96 * 32;
    char* dst0 = smem + (buf ? CW1 : CW0);
    for (int grp = wv; grp < 18; grp += 4) {
      int i = grp * 64 + lane;
      int dxi = i / 384;
      int rem = i - dxi * 384;
      int o = rem >> 2, q = rem & 3;
      gl16(wsrc + (size_t)dxi * 6144 + o * 32 + ((q ^ ((o >> 1) & 3)) << 3),
           dst0 + grp * 1024);
    }
  };

  stageP(iccB, 0, 0);
  stageW(iccB, 0, 0);
  __syncthreads();
  int cur = 0;
  for (int s = 0; s < 18; ++s) {
    if (s < 17) {
      const int ns = s + 1;
      const int nicc = iccB + ns / 3, ndy = ns - (ns / 3) * 3;
      stageP(nicc, ndy, cur ^ 1);
      stageW(nicc, ndy, cur ^ 1);
    }
    const char* Pb = smem + (cur ? CP1 : CP0);
    const char* Wb = smem + (cur ? CW1 : CW0);
#pragma unroll
    for (int dxi = 0; dxi < 3; ++dxi) {
      bh8 af[3];
#pragma unroll
      for (int m = 0; m < 3; ++m) {
        int o = og * 48 + m * 16 + lid;
        af[m] = *(const bh8*)(Wb + ((dxi * 96 + o) << 6) +
                              ((g ^ ((o >> 1) & 3)) << 4));
      }
#pragma unroll
      for (int n = 0; n < 4; ++n) {
        int slot = pg * 64 + n * 16 + lid + dxi;
        bh8 bf = *(const bh8*)(Pb + (slot << 6) + ((g ^ ((slot >> 1) & 3)) << 4));
#pragma unroll
        for (int m = 0; m < 3; ++m)
          acc[m][n] = __builtin_amdgcn_mfma_f32_16x16x32_bf16(
              af[m], bf, acc[m][n], 0, 0, 0);
      }
    }
    __syncthreads();
    cur ^= 1;
  }

  // epilogue: partial (pre-relu); bias folded into half 0 only.
  ushort* dst = half ? h1b : h1a;
  const size_t pxbase = (size_t)(b << 14) + y * 128 + pg * 64;
#pragma unroll
  for (int m = 0; m < 3; ++m) {
    const int ob = oh * 96 + og * 48 + m * 16 + g * 4;
    float4 bv = half ? make_float4(0.f, 0.f, 0.f, 0.f) : *(const float4*)(b1 + ob);
#pragma unroll
    for (int n = 0; n < 4; ++n) {
      size_t px = pxbase + n * 16 + lid;
      dst[(size_t)(ob + 0) * (NB * HW) + px] = f2bf(acc[m][n][0] + bv.x);
      dst[(size_t)(ob + 1) * (NB * HW) + px] = f2bf(acc[m][n][1] + bv.y);
      dst[(size_t)(ob + 2) * (NB * HW) + px] = f2bf(acc[m][n][2] + bv.z);
      dst[(size_t)(ob + 3) * (NB * HW) + px] = f2bf(acc[m][n][3] + bv.w);
    }
  }
}

// ---------------------------------------------------------------------------
// off head: fuses partial combine, v = relu(pa + pb).
// ---------------------------------------------------------------------------
__global__ __launch_bounds__(256) void k_offhead(
    const ushort* __restrict__ h1a, const ushort* __restrict__ h1b,
    const float* __restrict__ w2, const float* __restrict__ b2,
    float* __restrict__ off) {
  __shared__ float w2l[18 * NC];
  const int tid = threadIdx.x;
  for (int i = tid; i < 18 * NC; i += 256) w2l[i] = w2[i];
  __syncthreads();
  const int px = tid & 127;
  const int jh = tid >> 7;
  const size_t p = (size_t)blockIdx.x * 128 + px;
  float acc[9];
#pragma unroll
  for (int jj = 0; jj < 9; ++jj) acc[jj] = b2[jh * 9 + jj];
  for (int c = 0; c < NC; ++c) {
    float v = fmaxf(bf2f(h1a[(size_t)c * (NB * HW) + p]) +
                    bf2f(h1b[(size_t)c * (NB * HW) + p]), 0.f);
#pragma unroll
    for (int jj = 0; jj < 9; ++jj) acc[jj] += w2l[(jh * 9 + jj) * NC + c] * v;
  }
#pragma unroll
  for (int jj = 0; jj < 9; ++jj) off[p * 18 + jh * 9 + jj] = acc[jj];
}

// ---------------------------------------------------------------------------
// attn v8 (unchanged): kv-interleaved uint4 gathers, cvtpk packing.
// ---------------------------------------------------------------------------
__global__ __launch_bounds__(192, 6) void k_attn(
    const ushort* __restrict__ q, const ushort* __restrict__ kv,
    const float* __restrict__ off, ushort* __restrict__ pre) {
  const int s = threadIdx.x;          // 0..191
  const int pix = s / 48;
  const int sub = s - pix * 48;
  const int p = blockIdx.x * 4 + pix;
  const int b = p >> 14;
  const int pp = p & 16383;
  const int y = pp >> 7, x = pp & 127;

  uint2 qu = *(const uint2*)(q + (size_t)p * NC + 4 * sub);
  const float q0 = asf(qu.x << 16), q1 = asf(qu.x & 0xffff0000u);
  const float q2 = asf(qu.y << 16), q3 = asf(qu.y & 0xffff0000u);
  const ushort* kl = kv + (size_t)b * (HW * 384) + sub * 8;
  const int obase = b * HW;

  float pl[9];
  unsigned int vp0[9], vp1[9];
#pragma unroll
  for (int idx = 0; idx < 9; ++idx) {
    const int yy = y + idx / 3 - 1, xx = x + idx % 3 - 1;
    const bool inb = (yy >= 0) && (yy < 128) && (xx >= 0) && (xx < 128);
    float sx = 0.f, sy = 0.f;
    if (inb) {
      const int sp = obase + yy * 128 + xx;
      sx = off[sp * 18 + idx * 2 + 0];
      sy = off[sp * 18 + idx * 2 + 1];
    }
    const float fx0 = floorf(sx), fy0 = floorf(sy);
    const float wx1 = sx - fx0, wy1 = sy - fy0;
    const float wx0 = 1.f - wx1, wy0 = 1.f - wy1;
    const float inbf = inb ? 1.f : 0.f;
    const float wxm0 = wx0 * ((fx0 >= 0.f && fx0 <= 127.f) ? inbf : 0.f);
    const float wxm1 = wx1 * ((fx0 >= -1.f && fx0 <= 126.f) ? inbf : 0.f);
    const float wym0 = wy0 * ((fy0 >= 0.f && fy0 <= 127.f) ? 1.f : 0.f);
    const float wym1 = wy1 * ((fy0 >= -1.f && fy0 <= 126.f) ? 1.f : 0.f);
    const int ix0 = (int)fminf(fmaxf(fx0, 0.f), 127.f);
    const int iy0 = (int)fminf(fmaxf(fy0, 0.f), 127.f);
    const int ix1 = (int)fminf(fmaxf(fx0 + 1.f, 0.f), 127.f);
    const int iy1 = (int)fminf(fmaxf(fy0 + 1.f, 0.f), 127.f);
    const float w00 = wym0 * wxm0, w01 = wym0 * wxm1;
    const float w10 = wym1 * wxm0, w11 = wym1 * wxm1;
    const unsigned int e00 = (unsigned int)(iy0 * 128 + ix0) * 384u;
    const unsigned int e01 = (unsigned int)(iy0 * 128 + ix1) * 384u;
    const unsigned int e10 = (unsigned int)(iy1 * 128 + ix0) * 384u;
    const unsigned int e11 = (unsigned int)(iy1 * 128 + ix1) * 384u;
    float ks0 = 0.f, ks1 = 0.f, ks2 = 0.f, ks3 = 0.f;
    float vs0 = 0.f, vs1 = 0.f, vs2 = 0.f, vs3 = 0.f;
#define CORNER(W, E)                                            \
  {                                                             \
    uint4 kk = *(const uint4*)(kl + (E));                       \
    ks0 = fmaf((W), asf(kk.x << 16), ks0);                      \
    ks1 = fmaf((W), asf(kk.x & 0xffff0000u), ks1);              \
    ks2 = fmaf((W), asf(kk.y << 16), ks2);                      \
    ks3 = fmaf((W), asf(kk.y & 0xffff0000u), ks3);              \
    vs0 = fmaf((W), asf(kk.z << 16), vs0);                      \
    vs1 = fmaf((W), asf(kk.z & 0xffff0000u), vs1);              \
    vs2 = fmaf((W), asf(kk.w << 16), vs2);                      \
    vs3 = fmaf((W), asf(kk.w & 0xffff0000u), vs3);              \
  }
    CORNER(w00, e00)
    CORNER(w01, e01)
    CORNER(w10, e10)
    CORNER(w11, e11)
#undef CORNER
    float pd = q0 * ks0 + q1 * ks1 + q2 * ks2 + q3 * ks3;
    pd += __shfl_xor(pd, 1);
    pd += __shfl_xor(pd, 2);
    pd += __shfl_xor(pd, 4);
    pl[idx] = pd;
    vp0[idx] = cvtpk(vs0, vs1);
    vp1[idx] = cvtpk(vs2, vs3);
  }
  float mx = pl[0];
#pragma unroll
  for (int i = 1; i < 9; ++i) mx = fmaxf(mx, pl[i]);
  float sm = 0.f;
#pragma unroll
  for (int i = 0; i < 9; ++i) { pl[i] = __expf(pl[i] - mx); sm += pl[i]; }
  const float inv = __builtin_amdgcn_rcpf(sm);
  float o0 = 0.f, o1 = 0.f, o2 = 0.f, o3 = 0.f;
#pragma unroll
  for (int i = 0; i < 9; ++i) {
    const float a = pl[i] * inv;
    o0 = fmaf(a, asf(vp0[i] << 16), o0);
    o1 = fmaf(a, asf(vp0[i] & 0xffff0000u), o1);
    o2 = fmaf(a, asf(vp1[i] << 16), o2);
    o3 = fmaf(a, asf(vp1[i] & 0xffff0000u), o3);
  }
  ushort4 r;
  r.x = f2bf(o0); r.y = f2bf(o1); r.z = f2bf(o2); r.w = f2bf(o3);
  *(ushort4*)(pre + (size_t)p * NC + 4 * sub) = r;
}

extern "C" void kernel_launch(void* const* d_in, const int* in_sizes, int n_in,
                              void* d_out, int out_size, void* d_ws, size_t ws_size,
                              hipStream_t stream) {
  const float* x_q    = (const float*)d_in[0];
  const float* x_kv   = (const float*)d_in[1];
  const float* w_q    = (const float*)d_in[2];
  const float* w_kv   = (const float*)d_in[3];
  const float* w_off1 = (const float*)d_in[4];
  const float* b_off1 = (const float*)d_in[5];
  const float* w_off2 = (const float*)d_in[6];
  const float* b_off2 = (const float*)d_in[7];
  const float* w_proj = (const float*)d_in[8];
  const float* b_proj = (const float*)d_in[9];
  float* out = (float*)d_out;

  char* W = (char*)d_ws;
  const size_t SB = (size_t)NB * HW * NC * 2;  // 12,582,912 B
  ushort* qb   = (ushort*)W;                                 // SB
  ushort* kvb  = (ushort*)(W + SB);                          // 2*SB interleaved
  ushort* preb = (ushort*)(W + 3 * SB);                      // SB
  ushort* h1a  = preb;  // partial A (bf16) dead before attn writes preb
  ushort* wg   = (ushort*)(W + 4 * SB);                      //   294,912 B
  float*  offb = (float*)(W + 4 * SB + 294912);              // 2,359,296 B
  ushort* xpp  = (ushort*)(W + 4 * SB + 294912 + 2359296);   // 26,357,760 B
  ushort* h1b  = (ushort*)(W + 4 * SB + 294912 + 2359296 + 26357760);  // SB partial B
  ushort* wpk  = (ushort*)d_out;  // conv weights; proj overwrites later

  const float scale = 0.17677669529663687f;
  dim3 blk(256);
  k_wpack<<<dim3(2592), blk, 0, stream>>>(w_off1, wpk);
  k_wgpack<<<dim3(576), blk, 0, stream>>>(w_q, w_kv, w_proj, scale, wg);
  k_zerohalo<<<dim3(195), blk, 0, stream>>>(xpp);
  k_xpack<<<dim3(512, 2), blk, 0, stream>>>(x_q, x_kv, xpp);
  k_gemm_mfma<<<dim3(512, 3), blk, 0, stream>>>(xpp, wg, qb, kvb);
  k_conv_mfma<<<dim3(1024), blk, 0, stream>>>(xpp, wpk, b_off1, h1a, h1b);
  k_offhead<<<dim3(NB * 128), blk, 0, stream>>>(h1a, h1b, w_off2, b_off2, offb);
  k_attn<<<dim3(8192), dim3(192), 0, stream>>>(qb, kvb, offb, preb);
  k_proj_mfma<<<dim3(512, 3), blk, 0, stream>>>(preb, wg + 576 * NC, b_proj, out);
}

// Round 20
// 168.463 us; speedup vs baseline: 1.3941x; 1.3941x over previous
//
#include <hip/hip_runtime.h>
#include <math.h>

#define HW 16384
#define NB 2
#define NC 192

typedef __attribute__((ext_vector_type(8))) short bh8;
typedef __attribute__((ext_vector_type(4))) float f32x4;

__device__ inline ushort f2bf(float f) {
  union { float f; unsigned int u; } x; x.f = f;
  unsigned int r = x.u + 0x7fffu + ((x.u >> 16) & 1u);
  return (ushort)(r >> 16);
}
__device__ inline float bf2f(ushort u) {
  union { unsigned int i; float f; } x; x.i = ((unsigned int)u) << 16;
  return x.f;
}
__device__ inline float asf(unsigned int u) {
  union { unsigned int i; float f; } x; x.i = u; return x.f;
}
__device__ inline unsigned int cvtpk(float lo, float hi) {
  unsigned int r;
  asm("v_cvt_pk_bf16_f32 %0, %1, %2" : "=v"(r) : "v"(lo), "v"(hi));
  return r;
}
__device__ inline void gl16(const ushort* g, char* l) {
  __builtin_amdgcn_global_load_lds(
      (const __attribute__((address_space(1))) unsigned int*)g,
      (__attribute__((address_space(3))) unsigned int*)l, 16, 0, 0);
}

// ---------------------------------------------------------------------------
// Kernel 0a: pack conv weights -> wpack[s=108][o=192][kk=32] bf16 (in d_out)
// ---------------------------------------------------------------------------
__global__ void k_wpack(const float* __restrict__ w1, ushort* __restrict__ wpack) {
  int i = blockIdx.x * 256 + threadIdx.x;  // 663552
  int s = i / 6144;
  int rem = i - s * 6144;
  int o = rem >> 5, kk = rem & 31;
  int dy = s / 36, t2 = s - dy * 36;
  int icc = t2 / 3, dxi = t2 - icc * 3;
  int ic = icc * 32 + kk;
  wpack[i] = f2bf(w1[(size_t)o * 3456 + (size_t)ic * 9 + dy * 3 + dxi]);
}

// ---------------------------------------------------------------------------
// Kernel 0b: pack GEMM weights -> wg[768][192] bf16.
// ---------------------------------------------------------------------------
__global__ void k_wgpack(const float* __restrict__ wq, const float* __restrict__ wkv,
                         const float* __restrict__ wp, float scale,
                         ushort* __restrict__ wg) {
  int i = blockIdx.x * 256 + threadIdx.x;  // 147456
  int r = i / NC, c = i - r * NC;
  float v;
  if (r < 192) {
    int orow = (r & 31) * 6 + (r >> 5);
    v = wq[(size_t)orow * NC + c] * scale;
  } else if (r < 576) {
    int rp = r - 192;
    int t = rp >= 192 ? 1 : 0;
    int cc = rp - t * 192;
    int orow = t * 192 + (cc & 31) * 6 + (cc >> 5);
    v = wkv[(size_t)orow * NC + c];
  } else {
    int rp = r - 576;
    v = wp[(size_t)rp * NC + ((c & 31) * 6 + (c >> 5))];
  }
  wg[i] = f2bf(v);
}

// ---------------------------------------------------------------------------
// Kernel 0d: zero ONLY the halo of xpp. c = i % 48 (48 not a power of two).
// ---------------------------------------------------------------------------
__global__ void k_zerohalo(ushort* __restrict__ xpp) {
  int i = blockIdx.x * 256 + threadIdx.x;  // exactly 195*256 = 49920
  int t = i / 48;          // 0..1039
  int c = i - t * 48;      // 0..47
  int b = t / 520;
  int slot = t - b * 520;
  int row, px;
  if (slot < 132) { row = 0; px = slot; }
  else if (slot < 264) { row = 129; px = slot - 132; }
  else { int j = slot - 264; row = 1 + (j >> 1); px = (j & 1) ? 131 : 0; }
  *(uint4*)(xpp + ((size_t)(b * 130 + row) * 132 + px) * 384 + c * 8) =
      make_uint4(0u, 0u, 0u, 0u);
}

// ---------------------------------------------------------------------------
// Kernel 0c: x fp32 NCHW -> xpp bf16 padded NHWC [b][130 rows][132 px][384].
// ---------------------------------------------------------------------------
__global__ __launch_bounds__(256) void k_xpack(const float* __restrict__ xq,
                                               const float* __restrict__ xkv,
                                               ushort* __restrict__ xpp) {
  __shared__ float t[NC][65];
  const int tid = threadIdx.x;
  const size_t r0 = (size_t)blockIdx.x * 64;
  const int b = (int)(r0 >> 14);
  const int px0 = (int)(r0 & 16383);
  const int y = px0 >> 7, x0 = px0 & 127;
  const float* src = (blockIdx.y == 0 ? xq : xkv) + (size_t)b * NC * HW + px0;
#pragma unroll
  for (int it = 0; it < 12; ++it) {
    int i = it * 256 + tid;  // 3072
    int c = i >> 4, q4 = i & 15;
    float4 v = *(const float4*)(src + (size_t)c * HW + q4 * 4);
    t[c][q4 * 4 + 0] = v.x; t[c][q4 * 4 + 1] = v.y;
    t[c][q4 * 4 + 2] = v.z; t[c][q4 * 4 + 3] = v.w;
  }
  __syncthreads();
  ushort* dst = xpp + ((size_t)(b * 130 + y + 1) * 132 + x0 + 1) * 384 +
                blockIdx.y * 192;
#pragma unroll
  for (int it = 0; it < 6; ++it) {
    int i = it * 256 + tid;  // 1536
    int px = i / 24, ch = i - px * 24;
    ushort4 u0, u1;
    u0.x = f2bf(t[ch * 8 + 0][px]); u0.y = f2bf(t[ch * 8 + 1][px]);
    u0.z = f2bf(t[ch * 8 + 2][px]); u0.w = f2bf(t[ch * 8 + 3][px]);
    u1.x = f2bf(t[ch * 8 + 4][px]); u1.y = f2bf(t[ch * 8 + 5][px]);
    u1.z = f2bf(t[ch * 8 + 6][px]); u1.w = f2bf(t[ch * 8 + 7][px]);
    *(ushort4*)&dst[(size_t)px * 384 + ch * 8] = u0;
    *(ushort4*)&dst[(size_t)px * 384 + ch * 8 + 4] = u1;
  }
}

// ---------------------------------------------------------------------------
// MFMA GEMM engine helpers.
// ---------------------------------------------------------------------------
__device__ inline void stage64(ushort* lds, const ushort* src, int rowStride,
                               int tid) {
#pragma unroll
  for (int it = 0; it < 6; ++it) {
    int i = it * 256 + tid;  // 1536
    int row = i / 24, c = i - row * 24;
    int pos = (c & 24) | ((c & 7) ^ (row & 7));
    uint4 v = *(const uint4*)(src + (size_t)row * rowStride + c * 8);
    *(uint4*)&lds[row * NC + pos * 8] = v;
  }
}
__device__ inline bh8 frag64(const ushort* lds, int row, int c) {
  int pos = (c & 24) | ((c & 7) ^ (row & 7));
  return *(const bh8*)&lds[row * NC + pos * 8];
}

// ---------------------------------------------------------------------------
// Merged q/k/v GEMM: blockIdx.y = 0:q 1:k 2:v. x-tile staged once, loop 3 o-tiles.
// k/v write INTERLEAVED kvb[px][j][k4|v4] (16B per (px,j)).
// ---------------------------------------------------------------------------
__global__ __launch_bounds__(256) void k_gemm_mfma(
    const ushort* __restrict__ xpp, const ushort* __restrict__ wg,
    ushort* __restrict__ qb, ushort* __restrict__ kvb) {
  __shared__ __attribute__((aligned(16))) ushort xs[64 * NC];
  __shared__ __attribute__((aligned(16))) ushort ws2[64 * NC];
  const int tid = threadIdx.x;
  const size_t p0 = (size_t)blockIdx.x * 64;
  const int bb = (int)(p0 >> 14);
  const int yy = (int)((p0 >> 7) & 127);
  const int xx0 = (int)(p0 & 127);
  const int which = blockIdx.y;
  const int cOff = (which == 0) ? 0 : 192;
  const ushort* src = xpp + ((size_t)(bb * 130 + yy + 1) * 132 + xx0 + 1) * 384 + cOff;
  const ushort* wbase = wg + (size_t)(which * 192) * NC;
  stage64(xs, src, 384, tid);
  const int lid = tid & 15, g = (tid >> 4) & 3, wv = tid >> 6;
  const int wo = (wv & 1) * 32, wp = (wv >> 1) * 32;
  const int vofs = (which == 2) ? 4 : 0;
  for (int ot = 0; ot < 3; ++ot) {
    if (ot) __syncthreads();
    stage64(ws2, wbase + (size_t)(ot * 64) * NC, NC, tid);
    __syncthreads();
    f32x4 acc[2][2];
#pragma unroll
    for (int m = 0; m < 2; ++m)
#pragma unroll
      for (int n = 0; n < 2; ++n) acc[m][n] = (f32x4){0.f, 0.f, 0.f, 0.f};
#pragma unroll
    for (int k = 0; k < 6; ++k) {
      bh8 a0 = frag64(ws2, wo + lid, k * 4 + g);
      bh8 a1 = frag64(ws2, wo + 16 + lid, k * 4 + g);
      bh8 b0 = frag64(xs, wp + lid, k * 4 + g);
      bh8 b1 = frag64(xs, wp + 16 + lid, k * 4 + g);
      acc[0][0] = __builtin_amdgcn_mfma_f32_16x16x32_bf16(a0, b0, acc[0][0], 0, 0, 0);
      acc[0][1] = __builtin_amdgcn_mfma_f32_16x16x32_bf16(a0, b1, acc[0][1], 0, 0, 0);
      acc[1][0] = __builtin_amdgcn_mfma_f32_16x16x32_bf16(a1, b0, acc[1][0], 0, 0, 0);
      acc[1][1] = __builtin_amdgcn_mfma_f32_16x16x32_bf16(a1, b1, acc[1][1], 0, 0, 0);
    }
    const int od = ot * 64;
#pragma unroll
    for (int m = 0; m < 2; ++m)
#pragma unroll
      for (int n = 0; n < 2; ++n) {
        int orow = od + wo + m * 16 + g * 4;
        size_t px = p0 + wp + n * 16 + lid;
        ushort4 u;
        u.x = f2bf(acc[m][n][0]); u.y = f2bf(acc[m][n][1]);
        u.z = f2bf(acc[m][n][2]); u.w = f2bf(acc[m][n][3]);
        if (which == 0)
          *(ushort4*)&qb[px * NC + orow] = u;
        else
          *(ushort4*)&kvb[px * 384 + orow * 2 + vofs] = u;
      }
  }
}

__global__ __launch_bounds__(256) void k_proj_mfma(
    const ushort* __restrict__ pre, const ushort* __restrict__ wg,
    const float* __restrict__ bp, float* __restrict__ out) {
  __shared__ __attribute__((aligned(16))) ushort xs[64 * NC];
  __shared__ __attribute__((aligned(16))) ushort ws2[64 * NC];
  const int tid = threadIdx.x;
  const size_t p0 = (size_t)blockIdx.x * 64;
  const int o0 = blockIdx.y * 64;
  stage64(xs, pre + p0 * NC, NC, tid);
  stage64(ws2, wg + (size_t)o0 * NC, NC, tid);
  __syncthreads();
  const int lid = tid & 15, g = (tid >> 4) & 3, wv = tid >> 6;
  const int wo = (wv & 1) * 32, wp = (wv >> 1) * 32;
  f32x4 acc[2][2];
#pragma unroll
  for (int m = 0; m < 2; ++m)
#pragma unroll
    for (int n = 0; n < 2; ++n) acc[m][n] = (f32x4){0.f, 0.f, 0.f, 0.f};
#pragma unroll
  for (int k = 0; k < 6; ++k) {
    bh8 a0 = frag64(ws2, wo + lid, k * 4 + g);
    bh8 a1 = frag64(ws2, wo + 16 + lid, k * 4 + g);
    bh8 b0 = frag64(xs, wp + lid, k * 4 + g);
    bh8 b1 = frag64(xs, wp + 16 + lid, k * 4 + g);
    acc[0][0] = __builtin_amdgcn_mfma_f32_16x16x32_bf16(a0, b0, acc[0][0], 0, 0, 0);
    acc[0][1] = __builtin_amdgcn_mfma_f32_16x16x32_bf16(a0, b1, acc[0][1], 0, 0, 0);
    acc[1][0] = __builtin_amdgcn_mfma_f32_16x16x32_bf16(a1, b0, acc[1][0], 0, 0, 0);
    acc[1][1] = __builtin_amdgcn_mfma_f32_16x16x32_bf16(a1, b1, acc[1][1], 0, 0, 0);
  }
#pragma unroll
  for (int m = 0; m < 2; ++m)
#pragma unroll
    for (int n = 0; n < 2; ++n) {
      int oc = o0 + wo + m * 16 + g * 4;
      size_t pxf = p0 + wp + n * 16 + lid;
      int b = (int)(pxf >> 14);
      int px = (int)(pxf & 16383);
#pragma unroll
      for (int j = 0; j < 4; ++j)
        out[((size_t)b * NC + oc + j) * HW + px] = acc[m][n][j] + bp[oc + j];
    }
}

// ---------------------------------------------------------------------------
// Kernel 2 v6 (best measured): conv3x3 MFMA, W+P LDS dbuf, one barrier/step,
// XCD-aware block swizzle (T1): FETCH 89.5 -> 18.7 MB measured.
// ---------------------------------------------------------------------------
#define CP0 0
#define CP1 8448
#define CW0 16896
#define CW1 35328
__global__ __launch_bounds__(256, 3) void k_conv_mfma(
    const ushort* __restrict__ xpp, const ushort* __restrict__ wpack,
    const float* __restrict__ b1, ushort* __restrict__ h1) {
  __shared__ __attribute__((aligned(16))) char smem[53760];
  const int tid = threadIdx.x;
  // XCD swizzle: each XCD owns a contiguous 64-block chunk (bijective 512=8*64)
  const int bi = (blockIdx.x & 7) * 64 + (blockIdx.x >> 3);
  const int b = bi >> 8;
  const int y = (bi >> 1) & 127;
  const int oh = bi & 1;
  const int lid = tid & 15;
  const int g = (tid >> 4) & 3;
  const int wv = tid >> 6;
  const int lane = tid & 63;
  const int og = wv & 1;
  const int pg = wv >> 1;
  f32x4 acc[3][4];
#pragma unroll
  for (int m = 0; m < 3; ++m)
#pragma unroll
    for (int n = 0; n < 4; ++n) acc[m][n] = (f32x4){0.f, 0.f, 0.f, 0.f};

  auto stageP = [&](int icc, int dy, int buf) {
    const size_t rowbase = (size_t)(b * 130 + y + dy) * 132 * 384 + icc * 32;
    char* dst0 = smem + (buf ? CP1 : CP0);
    for (int grp = wv; grp < 9; grp += 4) {
      int i = grp * 64 + lane;
      if (i < 528) {
        int slot = i >> 2, ch = i & 3;
        gl16(xpp + rowbase + (size_t)slot * 384 + ((ch ^ ((slot >> 1) & 3)) << 3),
             dst0 + grp * 1024);
      }
    }
  };
  auto stageW = [&](int icc, int dy, int buf) {
    const ushort* wsrc = wpack + (size_t)((dy * 12 + icc) * 3) * 6144 + oh * 96 * 32;
    char* dst0 = smem + (buf ? CW1 : CW0);
    for (int grp = wv; grp < 18; grp += 4) {
      int i = grp * 64 + lane;
      int dxi = i / 384;
      int rem = i - dxi * 384;
      int o = rem >> 2, q = rem & 3;
      gl16(wsrc + (size_t)dxi * 6144 + o * 32 + ((q ^ ((o >> 1) & 3)) << 3),
           dst0 + grp * 1024);
    }
  };

  stageP(0, 0, 0);
  stageW(0, 0, 0);
  __syncthreads();
  int cur = 0;
  for (int s = 0; s < 36; ++s) {
    if (s < 35) {
      const int ns = s + 1;
      const int nicc = ns / 3, ndy = ns - nicc * 3;
      stageP(nicc, ndy, cur ^ 1);
      stageW(nicc, ndy, cur ^ 1);
    }
    const char* Pb = smem + (cur ? CP1 : CP0);
    const char* Wb = smem + (cur ? CW1 : CW0);
#pragma unroll
    for (int dxi = 0; dxi < 3; ++dxi) {
      bh8 af[3];
#pragma unroll
      for (int m = 0; m < 3; ++m) {
        int o = og * 48 + m * 16 + lid;
        af[m] = *(const bh8*)(Wb + ((dxi * 96 + o) << 6) +
                              ((g ^ ((o >> 1) & 3)) << 4));
      }
#pragma unroll
      for (int n = 0; n < 4; ++n) {
        int slot = pg * 64 + n * 16 + lid + dxi;
        bh8 bf = *(const bh8*)(Pb + (slot << 6) + ((g ^ ((slot >> 1) & 3)) << 4));
#pragma unroll
        for (int m = 0; m < 3; ++m)
          acc[m][n] = __builtin_amdgcn_mfma_f32_16x16x32_bf16(
              af[m], bf, acc[m][n], 0, 0, 0);
      }
    }
    __syncthreads();
    cur ^= 1;
  }

  const size_t pxbase = (size_t)(b << 14) + y * 128 + pg * 64;
#pragma unroll
  for (int m = 0; m < 3; ++m) {
    const int ob = oh * 96 + og * 48 + m * 16 + g * 4;
    float4 bv = *(const float4*)(b1 + ob);
#pragma unroll
    for (int n = 0; n < 4; ++n) {
      size_t px = pxbase + n * 16 + lid;
      h1[(size_t)(ob + 0) * (NB * HW) + px] = f2bf(fmaxf(acc[m][n][0] + bv.x, 0.f));
      h1[(size_t)(ob + 1) * (NB * HW) + px] = f2bf(fmaxf(acc[m][n][1] + bv.y, 0.f));
      h1[(size_t)(ob + 2) * (NB * HW) + px] = f2bf(fmaxf(acc[m][n][2] + bv.z, 0.f));
      h1[(size_t)(ob + 3) * (NB * HW) + px] = f2bf(fmaxf(acc[m][n][3] + bv.w, 0.f));
    }
  }
}

// ---------------------------------------------------------------------------
// off head (h1 bf16)
// ---------------------------------------------------------------------------
__global__ __launch_bounds__(256) void k_offhead(
    const ushort* __restrict__ h1, const float* __restrict__ w2,
    const float* __restrict__ b2, float* __restrict__ off) {
  __shared__ float w2l[18 * NC];
  const int tid = threadIdx.x;
  for (int i = tid; i < 18 * NC; i += 256) w2l[i] = w2[i];
  __syncthreads();
  const int px = tid & 127;
  const int jh = tid >> 7;
  const size_t p = (size_t)blockIdx.x * 128 + px;
  float acc[9];
#pragma unroll
  for (int jj = 0; jj < 9; ++jj) acc[jj] = b2[jh * 9 + jj];
  for (int c = 0; c < NC; ++c) {
    float v = bf2f(h1[(size_t)c * (NB * HW) + p]);
#pragma unroll
    for (int jj = 0; jj < 9; ++jj) acc[jj] += w2l[(jh * 9 + jj) * NC + c] * v;
  }
#pragma unroll
  for (int jj = 0; jj < 9; ++jj) off[p * 18 + jh * 9 + jj] = acc[jj];
}

// ---------------------------------------------------------------------------
// attn v8 (best measured): kv-interleaved uint4 gathers, cvtpk packing,
// in-register softmax, per-lane in-loop setup.
// ---------------------------------------------------------------------------
__global__ __launch_bounds__(192, 6) void k_attn(
    const ushort* __restrict__ q, const ushort* __restrict__ kv,
    const float* __restrict__ off, ushort* __restrict__ pre) {
  const int s = threadIdx.x;          // 0..191
  const int pix = s / 48;
  const int sub = s - pix * 48;
  const int p = blockIdx.x * 4 + pix;
  const int b = p >> 14;
  const int pp = p & 16383;
  const int y = pp >> 7, x = pp & 127;

  uint2 qu = *(const uint2*)(q + (size_t)p * NC + 4 * sub);
  const float q0 = asf(qu.x << 16), q1 = asf(qu.x & 0xffff0000u);
  const float q2 = asf(qu.y << 16), q3 = asf(qu.y & 0xffff0000u);
  const ushort* kl = kv + (size_t)b * (HW * 384) + sub * 8;
  const int obase = b * HW;

  float pl[9];
  unsigned int vp0[9], vp1[9];
#pragma unroll
  for (int idx = 0; idx < 9; ++idx) {
    const int yy = y + idx / 3 - 1, xx = x + idx % 3 - 1;
    const bool inb = (yy >= 0) && (yy < 128) && (xx >= 0) && (xx < 128);
    float sx = 0.f, sy = 0.f;
    if (inb) {
      const int sp = obase + yy * 128 + xx;
      sx = off[sp * 18 + idx * 2 + 0];
      sy = off[sp * 18 + idx * 2 + 1];
    }
    const float fx0 = floorf(sx), fy0 = floorf(sy);
    const float wx1 = sx - fx0, wy1 = sy - fy0;
    const float wx0 = 1.f - wx1, wy0 = 1.f - wy1;
    const float inbf = inb ? 1.f : 0.f;
    const float wxm0 = wx0 * ((fx0 >= 0.f && fx0 <= 127.f) ? inbf : 0.f);
    const float wxm1 = wx1 * ((fx0 >= -1.f && fx0 <= 126.f) ? inbf : 0.f);
    const float wym0 = wy0 * ((fy0 >= 0.f && fy0 <= 127.f) ? 1.f : 0.f);
    const float wym1 = wy1 * ((fy0 >= -1.f && fy0 <= 126.f) ? 1.f : 0.f);
    const int ix0 = (int)fminf(fmaxf(fx0, 0.f), 127.f);
    const int iy0 = (int)fminf(fmaxf(fy0, 0.f), 127.f);
    const int ix1 = (int)fminf(fmaxf(fx0 + 1.f, 0.f), 127.f);
    const int iy1 = (int)fminf(fmaxf(fy0 + 1.f, 0.f), 127.f);
    const float w00 = wym0 * wxm0, w01 = wym0 * wxm1;
    const float w10 = wym1 * wxm0, w11 = wym1 * wxm1;
    const unsigned int e00 = (unsigned int)(iy0 * 128 + ix0) * 384u;
    const unsigned int e01 = (unsigned int)(iy0 * 128 + ix1) * 384u;
    const unsigned int e10 = (unsigned int)(iy1 * 128 + ix0) * 384u;
    const unsigned int e11 = (unsigned int)(iy1 * 128 + ix1) * 384u;
    float ks0 = 0.f, ks1 = 0.f, ks2 = 0.f, ks3 = 0.f;
    float vs0 = 0.f, vs1 = 0.f, vs2 = 0.f, vs3 = 0.f;
#define CORNER(W, E)                                            \
  {                                                             \
    uint4 kk = *(const uint4*)(kl + (E));                       \
    ks0 = fmaf((W), asf(kk.x << 16), ks0);                      \
    ks1 = fmaf((W), asf(kk.x & 0xffff0000u), ks1);              \
    ks2 = fmaf((W), asf(kk.y << 16), ks2);                      \
    ks3 = fmaf((W), asf(kk.y & 0xffff0000u), ks3);              \
    vs0 = fmaf((W), asf(kk.z << 16), vs0);                      \
    vs1 = fmaf((W), asf(kk.z & 0xffff0000u), vs1);              \
    vs2 = fmaf((W), asf(kk.w << 16), vs2);                      \
    vs3 = fmaf((W), asf(kk.w & 0xffff0000u), vs3);              \
  }
    CORNER(w00, e00)
    CORNER(w01, e01)
    CORNER(w10, e10)
    CORNER(w11, e11)
#undef CORNER
    float pd = q0 * ks0 + q1 * ks1 + q2 * ks2 + q3 * ks3;
    pd += __shfl_xor(pd, 1);
    pd += __shfl_xor(pd, 2);
    pd += __shfl_xor(pd, 4);
    pl[idx] = pd;
    vp0[idx] = cvtpk(vs0, vs1);
    vp1[idx] = cvtpk(vs2, vs3);
  }
  float mx = pl[0];
#pragma unroll
  for (int i = 1; i < 9; ++i) mx = fmaxf(mx, pl[i]);
  float sm = 0.f;
#pragma unroll
  for (int i = 0; i < 9; ++i) { pl[i] = __expf(pl[i] - mx); sm += pl[i]; }
  const float inv = __builtin_amdgcn_rcpf(sm);
  float o0 = 0.f, o1 = 0.f, o2 = 0.f, o3 = 0.f;
#pragma unroll
  for (int i = 0; i < 9; ++i) {
    const float a = pl[i] * inv;
    o0 = fmaf(a, asf(vp0[i] << 16), o0);
    o1 = fmaf(a, asf(vp0[i] & 0xffff0000u), o1);
    o2 = fmaf(a, asf(vp1[i] << 16), o2);
    o3 = fmaf(a, asf(vp1[i] & 0xffff0000u), o3);
  }
  ushort4 r;
  r.x = f2bf(o0); r.y = f2bf(o1); r.z = f2bf(o2); r.w = f2bf(o3);
  *(ushort4*)(pre + (size_t)p * NC + 4 * sub) = r;
}

extern "C" void kernel_launch(void* const* d_in, const int* in_sizes, int n_in,
                              void* d_out, int out_size, void* d_ws, size_t ws_size,
                              hipStream_t stream) {
  const float* x_q    = (const float*)d_in[0];
  const float* x_kv   = (const float*)d_in[1];
  const float* w_q    = (const float*)d_in[2];
  const float* w_kv   = (const float*)d_in[3];
  const float* w_off1 = (const float*)d_in[4];
  const float* b_off1 = (const float*)d_in[5];
  const float* w_off2 = (const float*)d_in[6];
  const float* b_off2 = (const float*)d_in[7];
  const float* w_proj = (const float*)d_in[8];
  const float* b_proj = (const float*)d_in[9];
  float* out = (float*)d_out;

  char* W = (char*)d_ws;
  const size_t SB = (size_t)NB * HW * NC * 2;  // 12,582,912 B
  ushort* qb   = (ushort*)W;                                 // SB
  ushort* kvb  = (ushort*)(W + SB);                          // 2*SB interleaved
  ushort* preb = (ushort*)(W + 3 * SB);                      // SB
  ushort* h1b  = preb;  // h1 (bf16) dead before attn writes preb
  ushort* wg   = (ushort*)(W + 4 * SB);                      //   294,912 B
  float*  offb = (float*)(W + 4 * SB + 294912);              // 2,359,296 B
  ushort* xpp  = (ushort*)(W + 4 * SB + 294912 + 2359296);   // 26,357,760 B
  ushort* wpk  = (ushort*)d_out;  // conv weights; proj overwrites later

  const float scale = 0.17677669529663687f;
  dim3 blk(256);
  k_wpack<<<dim3(2592), blk, 0, stream>>>(w_off1, wpk);
  k_wgpack<<<dim3(576), blk, 0, stream>>>(w_q, w_kv, w_proj, scale, wg);
  k_zerohalo<<<dim3(195), blk, 0, stream>>>(xpp);
  k_xpack<<<dim3(512, 2), blk, 0, stream>>>(x_q, x_kv, xpp);
  k_gemm_mfma<<<dim3(512, 3), blk, 0, stream>>>(xpp, wg, qb, kvb);
  k_conv_mfma<<<dim3(512), blk, 0, stream>>>(xpp, wpk, b_off1, h1b);
  k_offhead<<<dim3(NB * 128), blk, 0, stream>>>(h1b, w_off2, b_off2, offb);
  k_attn<<<dim3(8192), dim3(192), 0, stream>>>(qb, kvb, offb, preb);
  k_proj_mfma<<<dim3(512, 3), blk, 0, stream>>>(preb, wg + 576 * NC, b_proj, out);
}